// Round 1
// baseline (1004.145 us; speedup 1.0000x reference)
//
#include <hip/hip_runtime.h>
#include <math.h>

#define TILE_BM 64
#define TILE_BN 64
#define TILE_BK 32
#define LDS_STRIDE 68   // 64 + 4 pad, keeps 16B alignment for float4 LDS reads

// ---------------------------------------------------------------------------
// C[M,N] = A[M,K] @ B[K,N] + bias[N]   (fp32, tiled, 4x4 micro-tile)
// ---------------------------------------------------------------------------
__global__ __launch_bounds__(256) void gemm_bias_f32(
    const float* __restrict__ A, const float* __restrict__ B,
    const float* __restrict__ bias, float* __restrict__ C,
    int M, int K, int N)
{
    __shared__ float As[TILE_BK * LDS_STRIDE];  // [k][m]
    __shared__ float Bs[TILE_BK * LDS_STRIDE];  // [k][n]
    const int tid = threadIdx.x;
    const int tx = tid & 15;
    const int ty = tid >> 4;
    const int m0 = blockIdx.x * TILE_BM;
    const int n0 = blockIdx.y * TILE_BN;

    float acc[4][4];
#pragma unroll
    for (int i = 0; i < 4; ++i)
#pragma unroll
        for (int j = 0; j < 4; ++j) acc[i][j] = 0.f;

    for (int k0 = 0; k0 < K; k0 += TILE_BK) {
        // A tile: 64 rows x 32 cols, store transposed [k][m]
#pragma unroll
        for (int it = 0; it < 2; ++it) {
            int idx = tid + it * 256;
            int row = idx >> 3;          // 0..63
            int c4  = (idx & 7) << 2;    // 0,4,..,28
            float4 v = make_float4(0.f, 0.f, 0.f, 0.f);
            int gr = m0 + row;
            if (gr < M) v = *(const float4*)(A + (size_t)gr * K + k0 + c4);
            As[(c4 + 0) * LDS_STRIDE + row] = v.x;
            As[(c4 + 1) * LDS_STRIDE + row] = v.y;
            As[(c4 + 2) * LDS_STRIDE + row] = v.z;
            As[(c4 + 3) * LDS_STRIDE + row] = v.w;
        }
        // B tile: 32 rows x 64 cols, direct [k][n]
#pragma unroll
        for (int it = 0; it < 2; ++it) {
            int idx = tid + it * 256;
            int r  = idx >> 4;           // 0..31
            int c4 = (idx & 15) << 2;    // 0,4,..,60
            float4 v = *(const float4*)(B + (size_t)(k0 + r) * N + n0 + c4);
            *(float4*)(Bs + r * LDS_STRIDE + c4) = v;
        }
        __syncthreads();
#pragma unroll
        for (int kk = 0; kk < TILE_BK; ++kk) {
            float4 a = *(const float4*)(As + kk * LDS_STRIDE + ty * 4);
            float4 b = *(const float4*)(Bs + kk * LDS_STRIDE + tx * 4);
            float av[4] = {a.x, a.y, a.z, a.w};
            float bv[4] = {b.x, b.y, b.z, b.w};
#pragma unroll
            for (int i = 0; i < 4; ++i)
#pragma unroll
                for (int j = 0; j < 4; ++j)
                    acc[i][j] = fmaf(av[i], bv[j], acc[i][j]);
        }
        __syncthreads();
    }

    float4 b4 = *(const float4*)(bias + n0 + tx * 4);
    float bb[4] = {b4.x, b4.y, b4.z, b4.w};
#pragma unroll
    for (int i = 0; i < 4; ++i) {
        int gr = m0 + ty * 4 + i;
        if (gr < M) {
            float4 o;
            o.x = acc[i][0] + bb[0];
            o.y = acc[i][1] + bb[1];
            o.z = acc[i][2] + bb[2];
            o.w = acc[i][3] + bb[3];
            *(float4*)(C + (size_t)gr * N + n0 + tx * 4) = o;
        }
    }
}

// ---------------------------------------------------------------------------
// CSR build: histogram -> single-block scan -> scatter
// ---------------------------------------------------------------------------
__global__ void hist_kernel(const int* __restrict__ rows, int* __restrict__ deg, int E)
{
    int i = blockIdx.x * 256 + threadIdx.x;
    if (i < E) atomicAdd(&deg[rows[i]], 1);
}

__global__ __launch_bounds__(256) void scan_kernel(
    const int* __restrict__ deg, int* __restrict__ rowptr,
    int* __restrict__ cursor, int n)
{
    __shared__ int sh[256];
    __shared__ int carry;
    int t = threadIdx.x;
    if (t == 0) carry = 0;
    __syncthreads();
    for (int base = 0; base < n; base += 256) {
        int v = (base + t < n) ? deg[base + t] : 0;
        sh[t] = v;
        __syncthreads();
        for (int off = 1; off < 256; off <<= 1) {
            int x = (t >= off) ? sh[t - off] : 0;
            __syncthreads();
            sh[t] += x;
            __syncthreads();
        }
        int excl = carry + sh[t] - v;
        if (base + t < n) { rowptr[base + t] = excl; cursor[base + t] = excl; }
        __syncthreads();
        if (t == 255) carry += sh[255];
        __syncthreads();
    }
    if (t == 0) rowptr[n] = carry;
}

__global__ void scatter_kernel(const int* __restrict__ rows, int* __restrict__ cursor,
                               int* __restrict__ eid, int E)
{
    int i = blockIdx.x * 256 + threadIdx.x;
    if (i < E) {
        int pos = atomicAdd(&cursor[rows[i]], 1);
        eid[pos] = i;
    }
}

// ---------------------------------------------------------------------------
// Fused SDDMM + online segment softmax + SpMM aggregate.
// One wave per node. Lane l owns flat features l*8 .. l*8+7  (d=l, h=0..7).
// v == k (source bug), so the K row loaded for the dot is reused for aggregation.
// QA is Q on input and is overwritten with the normalized aggregate (safe:
// only node i's wave touches row i of Q).
// ---------------------------------------------------------------------------
__global__ __launch_bounds__(256) void node_agg_kernel(
    float* __restrict__ QA, const float* __restrict__ Kb,
    const int* __restrict__ rowptr, const int* __restrict__ eid,
    const int* __restrict__ cols, int nN)
{
    int node = blockIdx.x * 4 + (threadIdx.x >> 6);
    int lane = threadIdx.x & 63;
    if (node >= nN) return;

    size_t qbase = (size_t)node * 512 + lane * 8;
    float4 qa = *(const float4*)(QA + qbase);
    float4 qb = *(const float4*)(QA + qbase + 4);
    float q[8] = {qa.x, qa.y, qa.z, qa.w, qb.x, qb.y, qb.z, qb.w};

    int start = rowptr[node];
    int end   = rowptr[node + 1];

    float m[8], den[8], acc[8];
#pragma unroll
    for (int h = 0; h < 8; ++h) {
        m[h] = -__builtin_huge_valf();
        den[h] = 0.f;
        acc[h] = 0.f;
    }

    for (int j = start; j < end; ++j) {
        int e = eid[j];
        int c = cols[e];
        size_t kbase = (size_t)c * 512 + lane * 8;
        float4 ka  = *(const float4*)(Kb + kbase);
        float4 kb2 = *(const float4*)(Kb + kbase + 4);
        float kv[8] = {ka.x, ka.y, ka.z, ka.w, kb2.x, kb2.y, kb2.z, kb2.w};

        float p[8];
#pragma unroll
        for (int h = 0; h < 8; ++h) p[h] = q[h] * kv[h];
        // butterfly sum over all 64 lanes (sum over d); every lane ends with s[h]
#pragma unroll
        for (int off = 1; off < 64; off <<= 1) {
#pragma unroll
            for (int h = 0; h < 8; ++h) p[h] += __shfl_xor(p[h], off, 64);
        }
        // online softmax update + aggregate
#pragma unroll
        for (int h = 0; h < 8; ++h) {
            float s  = p[h];
            float mn = fmaxf(m[h], s);
            float sc = __expf(m[h] - mn);   // exp(-inf)=0 on first edge
            float w  = __expf(s - mn);
            den[h] = den[h] * sc + w;
            acc[h] = acc[h] * sc + w * kv[h];
            m[h] = mn;
        }
    }

    bool has = end > start;
    float o[8];
#pragma unroll
    for (int h = 0; h < 8; ++h) o[h] = has ? acc[h] / den[h] : 0.f;
    float4 oa = make_float4(o[0], o[1], o[2], o[3]);
    float4 ob = make_float4(o[4], o[5], o[6], o[7]);
    *(float4*)(QA + qbase)     = oa;
    *(float4*)(QA + qbase + 4) = ob;
}

// ---------------------------------------------------------------------------
extern "C" void kernel_launch(void* const* d_in, const int* in_sizes, int n_in,
                              void* d_out, int out_size, void* d_ws, size_t ws_size,
                              hipStream_t stream)
{
    const float* h  = (const float*)d_in[0];
    const float* Wq = (const float*)d_in[1];
    const float* bq = (const float*)d_in[2];
    const float* Wk = (const float*)d_in[3];
    const float* bk = (const float*)d_in[4];
    const float* Wo = (const float*)d_in[5];
    const float* bo = (const float*)d_in[6];
    const int* rows = (const int*)d_in[7];
    const int* cols = (const int*)d_in[8];
    float* out = (float*)d_out;

    const int HID = 512;
    int nN = in_sizes[0] / HID;   // 25000
    int E  = in_sizes[7];         // 400000

    // workspace layout
    float* Q  = (float*)d_ws;                    // N*512 f32 (also AGG output)
    float* Kb = Q + (size_t)nN * HID;            // N*512 f32
    int* rowptr = (int*)(Kb + (size_t)nN * HID); // N+1
    int* cursor = rowptr + (nN + 1);             // N
    int* deg    = cursor + nN;                   // N
    int* eid    = deg + nN;                      // E

    // CSR build
    hipMemsetAsync(deg, 0, (size_t)nN * sizeof(int), stream);
    hist_kernel<<<(E + 255) / 256, 256, 0, stream>>>(rows, deg, E);
    scan_kernel<<<1, 256, 0, stream>>>(deg, rowptr, cursor, nN);
    scatter_kernel<<<(E + 255) / 256, 256, 0, stream>>>(rows, cursor, eid, E);

    // projections
    dim3 gg((nN + TILE_BM - 1) / TILE_BM, HID / TILE_BN);
    gemm_bias_f32<<<gg, 256, 0, stream>>>(h, Wq, bq, Q, nN, HID, HID);
    gemm_bias_f32<<<gg, 256, 0, stream>>>(h, Wk, bk, Kb, nN, HID, HID);

    // fused SDDMM + softmax + aggregate (writes AGG into Q buffer)
    node_agg_kernel<<<(nN + 3) / 4, 256, 0, stream>>>(Q, Kb, rowptr, eid, cols, nN);

    // output projection
    gemm_bias_f32<<<gg, 256, 0, stream>>>(Q, Wo, bo, out, nN, HID, HID);
}

// Round 2
// 402.023 us; speedup vs baseline: 2.4977x; 2.4977x over previous
//
#include <hip/hip_runtime.h>
#include <math.h>

typedef unsigned short u16;
typedef unsigned int u32;
typedef __attribute__((ext_vector_type(8))) short short8;    // bf16x8 MFMA frag
typedef __attribute__((ext_vector_type(8))) u16 ushort8;
typedef __attribute__((ext_vector_type(4))) float f32x4;

__device__ __forceinline__ float bf2f(u16 u) {
    union { u32 i; float f; } c; c.i = ((u32)u) << 16; return c.f;
}
__device__ __forceinline__ u16 f2bf(float f) {
    union { float f; u32 i; } c; c.f = f;
    u32 r = (c.i + 0x7FFFu + ((c.i >> 16) & 1u)) >> 16;
    return (u16)r;
}

// async global(16B) -> LDS, per-lane source addr, wave-linear LDS dest
__device__ __forceinline__ void gload16(void* lds, const void* g) {
    __builtin_amdgcn_global_load_lds(
        (const __attribute__((address_space(1))) u32*)g,
        (__attribute__((address_space(3))) u32*)lds,
        16, 0, 0);
}

// ---------------------------------------------------------------------------
// C[M,512] = A[M,512](bf16) @ Bt[512,512](bf16, [n][k]) + bias; m97 structure.
// OUTMODE 0: f32 store, 1: bf16 store. Stores guarded by row < Mout.
// ---------------------------------------------------------------------------
template <int OUTMODE>
__global__ __launch_bounds__(256) void gemm_mfma(
    const u16* __restrict__ A, const u16* __restrict__ Bt,
    const float* __restrict__ bias, void* __restrict__ Cout, int Mout)
{
    __shared__ u16 As[128 * 32];
    __shared__ u16 Bs[128 * 32];

    const int tid  = threadIdx.x;
    const int wave = tid >> 6;
    const int lane = tid & 63;
    const int m0 = blockIdx.x * 128;
    const int n0 = blockIdx.y * 128;
    const int wr = (wave >> 1) * 64;
    const int wc = (wave & 1) * 64;

    f32x4 acc[4][4];
#pragma unroll
    for (int i = 0; i < 4; ++i)
#pragma unroll
        for (int j = 0; j < 4; ++j) acc[i][j] = (f32x4){0.f, 0.f, 0.f, 0.f};

    // staging addresses: wave handles chunks (wave*2, wave*2+1) = rows wave*32..+31
    const int srow = lane >> 2;          // 0..15 within 16-row chunk
    const int scol = (lane & 3) * 8;     // bf16 elems
    const u16* gA = A  + (size_t)(m0 + wave * 32 + srow) * 512 + scol;
    const u16* gB = Bt + (size_t)(n0 + wave * 32 + srow) * 512 + scol;
    u16* lA = As + wave * 1024 + srow * 32 + scol;   // == wave_base + lane*8 elems
    u16* lB = Bs + wave * 1024 + srow * 32 + scol;

    const u16* pa = As + (wr + (lane & 15)) * 32 + (lane >> 4) * 8;
    const u16* pb = Bs + (wc + (lane & 15)) * 32 + (lane >> 4) * 8;

    for (int kt = 0; kt < 16; ++kt) {
        const int ko = kt * 32;
        gload16(lA,        gA + ko);
        gload16(lA + 512,  gA + ko + 16 * 512);
        gload16(lB,        gB + ko);
        gload16(lB + 512,  gB + ko + 16 * 512);
        __syncthreads();   // compiler drains vmcnt before barrier

        short8 af[4], bf[4];
#pragma unroll
        for (int i = 0; i < 4; ++i) af[i] = *(const short8*)(pa + i * 16 * 32);
#pragma unroll
        for (int j = 0; j < 4; ++j) bf[j] = *(const short8*)(pb + j * 16 * 32);
#pragma unroll
        for (int i = 0; i < 4; ++i)
#pragma unroll
            for (int j = 0; j < 4; ++j)
                acc[i][j] = __builtin_amdgcn_mfma_f32_16x16x32_bf16(
                    af[i], bf[j], acc[i][j], 0, 0, 0);
        __syncthreads();
    }

    // epilogue: C/D layout col=lane&15, row=(lane>>4)*4+reg
    const int ccol  = n0 + wc + (lane & 15);
    const int crow0 = m0 + wr + (lane >> 4) * 4;
#pragma unroll
    for (int j = 0; j < 4; ++j) {
        const float b = bias[ccol + j * 16];
#pragma unroll
        for (int i = 0; i < 4; ++i) {
#pragma unroll
            for (int r = 0; r < 4; ++r) {
                int row = crow0 + i * 16 + r;
                if (row < Mout) {
                    float v = acc[i][j][r] + b;
                    size_t off = (size_t)row * 512 + ccol + j * 16;
                    if (OUTMODE == 0) ((float*)Cout)[off] = v;
                    else              ((u16*)Cout)[off] = f2bf(v);
                }
            }
        }
    }
}

// ---------------------------------------------------------------------------
// prep kernels
// ---------------------------------------------------------------------------
// h f32 [nN][512] -> bf16 [nPad][512], pad rows zeroed
__global__ __launch_bounds__(256) void conv_h_k(
    const float* __restrict__ h, u16* __restrict__ hb, int nN)
{
    int t = blockIdx.x * 256 + threadIdx.x;      // one thread = 8 elems
    size_t e = (size_t)t * 8;
    int row = (int)(e >> 9);
    ushort8 o;
    if (row < nN) {
        f32x4 a = *(const f32x4*)(h + e);
        f32x4 b = *(const f32x4*)(h + e + 4);
#pragma unroll
        for (int i = 0; i < 4; ++i) { o[i] = f2bf(a[i]); o[i + 4] = f2bf(b[i]); }
    } else {
        o = (ushort8){0, 0, 0, 0, 0, 0, 0, 0};
    }
    *(ushort8*)(hb + e) = o;
}

// Wq/Wk: Wt[j][k] = bf16(W[k][(j&63)*8 + (j>>6)])   (B^T + head-major col perm)
__global__ __launch_bounds__(256) void conv_wqk(
    const float* __restrict__ W, u16* __restrict__ Wt)
{
    int t = blockIdx.x * 256 + threadIdx.x;
    int j = t >> 9, k = t & 511;
    int p = (j & 63) * 8 + (j >> 6);
    Wt[t] = f2bf(W[k * 512 + p]);
}

// Wo: Wot[c][j] = bf16(Wo[(j&63)*8 + (j>>6)][c])    (B^T + head-major row perm)
__global__ __launch_bounds__(256) void conv_wo(
    const float* __restrict__ W, u16* __restrict__ Wt)
{
    int t = blockIdx.x * 256 + threadIdx.x;
    int c = t >> 9, j = t & 511;
    int p = (j & 63) * 8 + (j >> 6);
    Wt[t] = f2bf(W[p * 512 + c]);
}

__global__ void conv_bias(const float* __restrict__ bq, const float* __restrict__ bk,
                          float* __restrict__ bqp, float* __restrict__ bkp)
{
    int j = blockIdx.x * 256 + threadIdx.x;
    if (j < 512) {
        int p = (j & 63) * 8 + (j >> 6);
        bqp[j] = bq[p];
        bkp[j] = bk[p];
    }
}

// ---------------------------------------------------------------------------
// CSR build
// ---------------------------------------------------------------------------
__global__ void hist_kernel(const int* __restrict__ rows, int* __restrict__ deg, int E)
{
    int i = blockIdx.x * 256 + threadIdx.x;
    if (i < E) atomicAdd(&deg[rows[i]], 1);
}

__global__ __launch_bounds__(256) void scan_kernel(
    const int* __restrict__ deg, int* __restrict__ rowptr,
    int* __restrict__ cursor, int n)
{
    __shared__ int sh[256];
    __shared__ int carry;
    int t = threadIdx.x;
    if (t == 0) carry = 0;
    __syncthreads();
    for (int base = 0; base < n; base += 256) {
        int v = (base + t < n) ? deg[base + t] : 0;
        sh[t] = v;
        __syncthreads();
        for (int off = 1; off < 256; off <<= 1) {
            int x = (t >= off) ? sh[t - off] : 0;
            __syncthreads();
            sh[t] += x;
            __syncthreads();
        }
        int excl = carry + sh[t] - v;
        if (base + t < n) { rowptr[base + t] = excl; cursor[base + t] = excl; }
        __syncthreads();
        if (t == 255) carry += sh[255];
        __syncthreads();
    }
    if (t == 0) rowptr[n] = carry;
}

__global__ void scatter_kernel(const int* __restrict__ rows, int* __restrict__ cursor,
                               int* __restrict__ eid, int E)
{
    int i = blockIdx.x * 256 + threadIdx.x;
    if (i < E) {
        int pos = atomicAdd(&cursor[rows[i]], 1);
        eid[pos] = i;
    }
}

// ---------------------------------------------------------------------------
// Fused SDDMM + online segment softmax + SpMM. Head-major layout:
// lane l -> head l>>3, dims (l&7)*8..+7. One wave per node.
// v == k (source bug): K row loaded for the dot is reused for aggregation.
// ---------------------------------------------------------------------------
__global__ __launch_bounds__(256) void node_agg(
    const float* __restrict__ Q, const u16* __restrict__ Kb,
    const int* __restrict__ rowptr, const int* __restrict__ eid,
    const int* __restrict__ cols, u16* __restrict__ aggb,
    int nN, int nPad)
{
    int node = blockIdx.x * 4 + (threadIdx.x >> 6);
    int lane = threadIdx.x & 63;
    if (node >= nPad) return;
    size_t base = (size_t)node * 512 + lane * 8;

    if (node >= nN) {
        *(ushort8*)(aggb + base) = (ushort8){0, 0, 0, 0, 0, 0, 0, 0};
        return;
    }

    float q[8];
    {
        f32x4 qa = *(const f32x4*)(Q + base);
        f32x4 qb = *(const f32x4*)(Q + base + 4);
#pragma unroll
        for (int i = 0; i < 4; ++i) { q[i] = qa[i]; q[i + 4] = qb[i]; }
    }

    int start = rowptr[node];
    int end   = rowptr[node + 1];

    float m = -__builtin_inff();
    float den = 0.f;
    float acc[8];
#pragma unroll
    for (int i = 0; i < 8; ++i) acc[i] = 0.f;

    for (int j = start; j < end; ++j) {
        int c = cols[eid[j]];
        ushort8 kv = *(const ushort8*)(Kb + (size_t)c * 512 + lane * 8);
        float kf[8];
#pragma unroll
        for (int i = 0; i < 8; ++i) kf[i] = bf2f(kv[i]);

        float p = 0.f;
#pragma unroll
        for (int i = 0; i < 8; ++i) p = fmaf(q[i], kf[i], p);
        p += __shfl_xor(p, 1, 64);
        p += __shfl_xor(p, 2, 64);
        p += __shfl_xor(p, 4, 64);

        // defer-max (T13, THR=8): rescale only when max grows materially
        if (p > m + 8.f) {
            float sc = __expf(m - p);   // first edge: exp(-inf)=0
            den *= sc;
#pragma unroll
            for (int i = 0; i < 8; ++i) acc[i] *= sc;
            m = p;
        }
        float w = __expf(p - m);        // bounded by e^8
        den += w;
#pragma unroll
        for (int i = 0; i < 8; ++i) acc[i] = fmaf(w, kf[i], acc[i]);
    }

    float inv = (end > start) ? 1.f / den : 0.f;
    ushort8 o;
#pragma unroll
    for (int i = 0; i < 8; ++i) o[i] = f2bf(acc[i] * inv);
    *(ushort8*)(aggb + base) = o;
}

// ---------------------------------------------------------------------------
extern "C" void kernel_launch(void* const* d_in, const int* in_sizes, int n_in,
                              void* d_out, int out_size, void* d_ws, size_t ws_size,
                              hipStream_t stream)
{
    const float* h  = (const float*)d_in[0];
    const float* Wq = (const float*)d_in[1];
    const float* bq = (const float*)d_in[2];
    const float* Wk = (const float*)d_in[3];
    const float* bk = (const float*)d_in[4];
    const float* Wo = (const float*)d_in[5];
    const float* bo = (const float*)d_in[6];
    const int* rows = (const int*)d_in[7];
    const int* cols = (const int*)d_in[8];
    float* out = (float*)d_out;

    const int HID = 512;
    const int nN  = in_sizes[0] / HID;              // 25000
    const int E   = in_sizes[7];                    // 400000
    const int nPad = (nN + 127) & ~127;             // 25088

    // workspace layout (bytes, all 16B-aligned)
    char* w = (char*)d_ws;
    float* Q    = (float*)w;                 w += (size_t)nPad * HID * 4;  // 51.4 MB
    u16*   Kb   = (u16*)w;                   w += (size_t)nPad * HID * 2;  // 25.7 MB
    u16*   hb   = (u16*)w;                   w += (size_t)nPad * HID * 2;  // 25.7 MB (reused as aggb)
    u16*   Wqt  = (u16*)w;                   w += 512 * 512 * 2;
    u16*   Wkt  = (u16*)w;                   w += 512 * 512 * 2;
    u16*   Wot  = (u16*)w;                   w += 512 * 512 * 2;
    float* bqp  = (float*)w;                 w += 512 * 4;
    float* bkp  = (float*)w;                 w += 512 * 4;
    int* rowptr = (int*)w;                   w += (size_t)(nN + 1) * 4;
    int* cursor = (int*)w;                   w += (size_t)nN * 4;
    int* deg    = (int*)w;                   w += (size_t)nN * 4;
    int* eid    = (int*)w;                   /* E*4 */

    // CSR build
    hipMemsetAsync(deg, 0, (size_t)nN * sizeof(int), stream);
    hist_kernel<<<(E + 255) / 256, 256, 0, stream>>>(rows, deg, E);
    scan_kernel<<<1, 256, 0, stream>>>(deg, rowptr, cursor, nN);
    scatter_kernel<<<(E + 255) / 256, 256, 0, stream>>>(rows, cursor, eid, E);

    // conversions
    conv_h_k<<<(nPad * (HID / 8) + 255) / 256, 256, 0, stream>>>(h, hb, nN);
    conv_wqk<<<1024, 256, 0, stream>>>(Wq, Wqt);
    conv_wqk<<<1024, 256, 0, stream>>>(Wk, Wkt);
    conv_wo <<<1024, 256, 0, stream>>>(Wo, Wot);
    conv_bias<<<2, 256, 0, stream>>>(bq, bk, bqp, bkp);

    // projections (head-major outputs)
    dim3 gg(nPad / 128, HID / 128);
    gemm_mfma<0><<<gg, 256, 0, stream>>>(hb, Wqt, bqp, Q,  nPad);   // Q f32
    gemm_mfma<1><<<gg, 256, 0, stream>>>(hb, Wkt, bkp, Kb, nPad);   // K bf16

    // fused SDDMM + softmax + aggregate -> bf16 agg (overwrites hb)
    node_agg<<<nPad / 4, 256, 0, stream>>>(Q, Kb, rowptr, eid, cols, hb, nN, nPad);

    // output projection
    gemm_mfma<0><<<gg, 256, 0, stream>>>(hb, Wot, bo, out, nN);
}

// Round 3
// 350.875 us; speedup vs baseline: 2.8618x; 1.1458x over previous
//
#include <hip/hip_runtime.h>
#include <math.h>

typedef unsigned short u16;
typedef unsigned int u32;
typedef __attribute__((ext_vector_type(8))) short short8;    // bf16x8 MFMA frag
typedef __attribute__((ext_vector_type(8))) u16 ushort8;
typedef __attribute__((ext_vector_type(4))) float f32x4;

__device__ __forceinline__ float bf2f(u16 u) {
    union { u32 i; float f; } c; c.i = ((u32)u) << 16; return c.f;
}
__device__ __forceinline__ u16 f2bf(float f) {
    union { float f; u32 i; } c; c.f = f;
    u32 r = (c.i + 0x7FFFu + ((c.i >> 16) & 1u)) >> 16;
    return (u16)r;
}

// async global(16B) -> LDS, per-lane source addr, wave-linear LDS dest
__device__ __forceinline__ void gload16(void* lds, const void* g) {
    __builtin_amdgcn_global_load_lds(
        (const __attribute__((address_space(1))) u32*)g,
        (__attribute__((address_space(3))) u32*)lds,
        16, 0, 0);
}

// ---------------------------------------------------------------------------
// C[M,512] = A[M,512] @ Bt[512,512]([n][k]) + bias.
// SPLIT=1: A,B given as bf16 hi+lo pairs; C = Ahi*Bhi + Alo*Bhi + Ahi*Blo.
// OUTMODE 0: f32 store, 1: bf16 store. Stores guarded by row < Mout.
// ---------------------------------------------------------------------------
template <int SPLIT, int OUTMODE>
__global__ __launch_bounds__(256) void gemm_mfma(
    const u16* __restrict__ Ahi, const u16* __restrict__ Alo,
    const u16* __restrict__ Bhi, const u16* __restrict__ Blo,
    const float* __restrict__ bias, void* __restrict__ Cout, int Mout)
{
    constexpr int NB = SPLIT ? 2 : 1;
    __shared__ u16 As[NB][128 * 32];
    __shared__ u16 Bs[NB][128 * 32];

    const int tid  = threadIdx.x;
    const int wave = tid >> 6;
    const int lane = tid & 63;
    const int m0 = blockIdx.x * 128;
    const int n0 = blockIdx.y * 128;
    const int wr = (wave >> 1) * 64;
    const int wc = (wave & 1) * 64;

    f32x4 acc[4][4];
#pragma unroll
    for (int i = 0; i < 4; ++i)
#pragma unroll
        for (int j = 0; j < 4; ++j) acc[i][j] = (f32x4){0.f, 0.f, 0.f, 0.f};

    // staging: wave handles rows wave*32 .. +31 of the 128-row tile
    const int srow = lane >> 2;          // 0..15 within 16-row chunk
    const int scol = (lane & 3) * 8;     // bf16 elems
    const size_t gOffA = (size_t)(m0 + wave * 32 + srow) * 512 + scol;
    const size_t gOffB = (size_t)(n0 + wave * 32 + srow) * 512 + scol;
    const int lOff = wave * 1024 + srow * 32 + scol;   // == wave_base + lane*16B

    const int paOff = (wr + (lane & 15)) * 32 + (lane >> 4) * 8;
    const int pbOff = (wc + (lane & 15)) * 32 + (lane >> 4) * 8;

    for (int kt = 0; kt < 16; ++kt) {
        const int ko = kt * 32;
        gload16(&As[0][lOff],       Ahi + gOffA + ko);
        gload16(&As[0][lOff + 512], Ahi + gOffA + ko + 16 * 512);
        gload16(&Bs[0][lOff],       Bhi + gOffB + ko);
        gload16(&Bs[0][lOff + 512], Bhi + gOffB + ko + 16 * 512);
        if constexpr (SPLIT) {
            gload16(&As[1][lOff],       Alo + gOffA + ko);
            gload16(&As[1][lOff + 512], Alo + gOffA + ko + 16 * 512);
            gload16(&Bs[1][lOff],       Blo + gOffB + ko);
            gload16(&Bs[1][lOff + 512], Blo + gOffB + ko + 16 * 512);
        }
        __syncthreads();   // compiler drains vmcnt before barrier

        short8 af[NB][4], bf[NB][4];
#pragma unroll
        for (int i = 0; i < 4; ++i) af[0][i] = *(const short8*)(&As[0][paOff + i * 16 * 32]);
#pragma unroll
        for (int j = 0; j < 4; ++j) bf[0][j] = *(const short8*)(&Bs[0][pbOff + j * 16 * 32]);
        if constexpr (SPLIT) {
#pragma unroll
            for (int i = 0; i < 4; ++i) af[1][i] = *(const short8*)(&As[1][paOff + i * 16 * 32]);
#pragma unroll
            for (int j = 0; j < 4; ++j) bf[1][j] = *(const short8*)(&Bs[1][pbOff + j * 16 * 32]);
        }
#pragma unroll
        for (int i = 0; i < 4; ++i)
#pragma unroll
            for (int j = 0; j < 4; ++j) {
                acc[i][j] = __builtin_amdgcn_mfma_f32_16x16x32_bf16(
                    af[0][i], bf[0][j], acc[i][j], 0, 0, 0);
                if constexpr (SPLIT) {
                    acc[i][j] = __builtin_amdgcn_mfma_f32_16x16x32_bf16(
                        af[1][i], bf[0][j], acc[i][j], 0, 0, 0);
                    acc[i][j] = __builtin_amdgcn_mfma_f32_16x16x32_bf16(
                        af[0][i], bf[1][j], acc[i][j], 0, 0, 0);
                }
            }
        __syncthreads();
    }

    // epilogue: C/D layout col=lane&15, row=(lane>>4)*4+reg
    const int ccol  = n0 + wc + (lane & 15);
    const int crow0 = m0 + wr + (lane >> 4) * 4;
#pragma unroll
    for (int j = 0; j < 4; ++j) {
        const float b = bias[ccol + j * 16];
#pragma unroll
        for (int i = 0; i < 4; ++i) {
#pragma unroll
            for (int r = 0; r < 4; ++r) {
                int row = crow0 + i * 16 + r;
                if (row < Mout) {
                    float v = acc[i][j][r] + b;
                    size_t off = (size_t)row * 512 + ccol + j * 16;
                    if (OUTMODE == 0) ((float*)Cout)[off] = v;
                    else              ((u16*)Cout)[off] = f2bf(v);
                }
            }
        }
    }
}

// ---------------------------------------------------------------------------
// prep: h f32 -> bf16 hi+lo, pad rows zeroed
// ---------------------------------------------------------------------------
__global__ __launch_bounds__(256) void conv_h(
    const float* __restrict__ h, u16* __restrict__ hhi, u16* __restrict__ hlo, int nN)
{
    int t = blockIdx.x * 256 + threadIdx.x;      // one thread = 8 elems
    size_t e = (size_t)t * 8;
    int row = (int)(e >> 9);
    ushort8 ohi, olo;
    if (row < nN) {
        f32x4 a = *(const f32x4*)(h + e);
        f32x4 b = *(const f32x4*)(h + e + 4);
        float x[8] = {a.x, a.y, a.z, a.w, b.x, b.y, b.z, b.w};
#pragma unroll
        for (int i = 0; i < 8; ++i) {
            u16 hi = f2bf(x[i]);
            ohi[i] = hi;
            olo[i] = f2bf(x[i] - bf2f(hi));
        }
    } else {
        ohi = (ushort8){0,0,0,0,0,0,0,0};
        olo = (ushort8){0,0,0,0,0,0,0,0};
    }
    *(ushort8*)(hhi + e) = ohi;
    *(ushort8*)(hlo + e) = olo;
}

// all weight/bias conversions in one kernel.
// Wq/Wk: Wt[j][k] = W[k][perm(j)] hi+lo  (B^T + head-major col perm)
// Wo:    Wot[c][j] = bf16(Wo[perm(j)][c])
__global__ __launch_bounds__(256) void conv_weights(
    const float* __restrict__ Wq, const float* __restrict__ Wk,
    const float* __restrict__ Wo, const float* __restrict__ bq,
    const float* __restrict__ bk,
    u16* __restrict__ Wqhi, u16* __restrict__ Wqlo,
    u16* __restrict__ Wkhi, u16* __restrict__ Wklo,
    u16* __restrict__ Wot, float* __restrict__ bqp, float* __restrict__ bkp)
{
    int t = blockIdx.x * 256 + threadIdx.x;
    if (t >= 512 * 512) return;
    int j = t >> 9, k = t & 511;
    int p = (j & 63) * 8 + (j >> 6);
    float wq = Wq[k * 512 + p];
    u16 hi = f2bf(wq);
    Wqhi[t] = hi; Wqlo[t] = f2bf(wq - bf2f(hi));
    float wk = Wk[k * 512 + p];
    hi = f2bf(wk);
    Wkhi[t] = hi; Wklo[t] = f2bf(wk - bf2f(hi));
    // Wo with row-perm, transposed: t = c*512 + j2
    int c = t >> 9, j2 = t & 511;
    int p2 = (j2 & 63) * 8 + (j2 >> 6);
    Wot[t] = f2bf(Wo[p2 * 512 + c]);
    if (t < 512) {
        int pp = (t & 63) * 8 + (t >> 6);
        bqp[t] = bq[pp];
        bkp[t] = bk[pp];
    }
}

// ---------------------------------------------------------------------------
// CSR build: histogram -> hierarchical scan -> scatter
// ---------------------------------------------------------------------------
__global__ void hist_kernel(const int* __restrict__ rows, int* __restrict__ deg, int E)
{
    int i = blockIdx.x * 256 + threadIdx.x;
    if (i < E) atomicAdd(&deg[rows[i]], 1);
}

#define SCAN_CHUNK 2048

__global__ __launch_bounds__(256) void scan_partial(
    const int* __restrict__ deg, int* __restrict__ bsum, int n)
{
    int base = blockIdx.x * SCAN_CHUNK;
    int t = threadIdx.x;
    int s = 0;
    for (int i = t; i < SCAN_CHUNK; i += 256) {
        int g = base + i;
        s += (g < n) ? deg[g] : 0;
    }
#pragma unroll
    for (int off = 1; off < 64; off <<= 1) s += __shfl_xor(s, off, 64);
    __shared__ int ws[4];
    if ((t & 63) == 0) ws[t >> 6] = s;
    __syncthreads();
    if (t == 0) bsum[blockIdx.x] = ws[0] + ws[1] + ws[2] + ws[3];
}

__global__ __launch_bounds__(64) void scan_bsum(
    int* __restrict__ bsum, int nb, int* __restrict__ rowptr, int n)
{
    int l = threadIdx.x;
    int v = (l < nb) ? bsum[l] : 0;
    int orig = v;
#pragma unroll
    for (int off = 1; off < 64; off <<= 1) {
        int x = __shfl_up(v, off, 64);
        if (l >= off) v += x;
    }
    if (l < nb) bsum[l] = v - orig;       // exclusive
    if (l == nb - 1) rowptr[n] = v;       // total
}

__global__ __launch_bounds__(256) void scan_final(
    const int* __restrict__ deg, const int* __restrict__ bsum,
    int* __restrict__ rowptr, int* __restrict__ cursor, int n)
{
    int t = threadIdx.x;
    int base = blockIdx.x * SCAN_CHUNK + t * 8;
    int v[8];
    int s = 0;
#pragma unroll
    for (int i = 0; i < 8; ++i) {
        int g = base + i;
        v[i] = (g < n) ? deg[g] : 0;
        s += v[i];
    }
    int lane = t & 63, w = t >> 6;
    int inc = s;
#pragma unroll
    for (int off = 1; off < 64; off <<= 1) {
        int x = __shfl_up(inc, off, 64);
        if (lane >= off) inc += x;
    }
    __shared__ int wsum[4];
    if (lane == 63) wsum[w] = inc;
    __syncthreads();
    int excl = bsum[blockIdx.x] + inc - s;
    for (int i = 0; i < w; ++i) excl += wsum[i];
#pragma unroll
    for (int i = 0; i < 8; ++i) {
        int g = base + i;
        if (g < n) { rowptr[g] = excl; cursor[g] = excl; }
        excl += v[i];
    }
}

__global__ void scatter_kernel(const int* __restrict__ rows, int* __restrict__ cursor,
                               int* __restrict__ eid, int E)
{
    int i = blockIdx.x * 256 + threadIdx.x;
    if (i < E) {
        int pos = atomicAdd(&cursor[rows[i]], 1);
        eid[pos] = i;
    }
}

// ---------------------------------------------------------------------------
// Fused SDDMM + online segment softmax + SpMM. Head-major layout:
// lane l -> head l>>3, dims (l&7)*8..+7. One wave per node.
// v == k (source bug): K row loaded for the dot is reused for aggregation.
// ---------------------------------------------------------------------------
__global__ __launch_bounds__(256) void node_agg(
    const float* __restrict__ Q, const u16* __restrict__ Kb,
    const int* __restrict__ rowptr, const int* __restrict__ eid,
    const int* __restrict__ cols, u16* __restrict__ aggb,
    int nN, int nPad)
{
    int node = blockIdx.x * 4 + (threadIdx.x >> 6);
    int lane = threadIdx.x & 63;
    if (node >= nPad) return;
    size_t base = (size_t)node * 512 + lane * 8;

    if (node >= nN) {
        *(ushort8*)(aggb + base) = (ushort8){0,0,0,0,0,0,0,0};
        return;
    }

    float q[8];
    {
        f32x4 qa = *(const f32x4*)(Q + base);
        f32x4 qb = *(const f32x4*)(Q + base + 4);
#pragma unroll
        for (int i = 0; i < 4; ++i) { q[i] = qa[i]; q[i + 4] = qb[i]; }
    }

    int start = rowptr[node];
    int end   = rowptr[node + 1];

    float m = -__builtin_inff();
    float den = 0.f;
    float acc[8];
#pragma unroll
    for (int i = 0; i < 8; ++i) acc[i] = 0.f;

    for (int j = start; j < end; ++j) {
        int c = cols[eid[j]];
        ushort8 kv = *(const ushort8*)(Kb + (size_t)c * 512 + lane * 8);
        float kf[8];
#pragma unroll
        for (int i = 0; i < 8; ++i) kf[i] = bf2f(kv[i]);

        float p = 0.f;
#pragma unroll
        for (int i = 0; i < 8; ++i) p = fmaf(q[i], kf[i], p);
        p += __shfl_xor(p, 1, 64);
        p += __shfl_xor(p, 2, 64);
        p += __shfl_xor(p, 4, 64);

        // defer-max (T13, THR=8): rescale only when max grows materially
        if (p > m + 8.f) {
            float sc = __expf(m - p);   // first edge: exp(-inf)=0
            den *= sc;
#pragma unroll
            for (int i = 0; i < 8; ++i) acc[i] *= sc;
            m = p;
        }
        float w = __expf(p - m);        // bounded by e^8
        den += w;
#pragma unroll
        for (int i = 0; i < 8; ++i) acc[i] = fmaf(w, kf[i], acc[i]);
    }

    float inv = (end > start) ? 1.f / den : 0.f;
    ushort8 o;
#pragma unroll
    for (int i = 0; i < 8; ++i) o[i] = f2bf(acc[i] * inv);
    *(ushort8*)(aggb + base) = o;
}

// ---------------------------------------------------------------------------
extern "C" void kernel_launch(void* const* d_in, const int* in_sizes, int n_in,
                              void* d_out, int out_size, void* d_ws, size_t ws_size,
                              hipStream_t stream)
{
    const float* h  = (const float*)d_in[0];
    const float* Wq = (const float*)d_in[1];
    const float* bq = (const float*)d_in[2];
    const float* Wk = (const float*)d_in[3];
    const float* bk = (const float*)d_in[4];
    const float* Wo = (const float*)d_in[5];
    const float* bo = (const float*)d_in[6];
    const int* rows = (const int*)d_in[7];
    const int* cols = (const int*)d_in[8];
    float* out = (float*)d_out;

    const int HID = 512;
    const int nN  = in_sizes[0] / HID;              // 25000
    const int E   = in_sizes[7];                    // 400000
    const int nPad = (nN + 127) & ~127;             // 25088
    const int nb = (nN + SCAN_CHUNK - 1) / SCAN_CHUNK;  // 13

    // Q (f32) lives in d_out: it is fully consumed by node_agg before the
    // final Wo GEMM overwrites d_out with the real output.
    float* Q = out;

    // workspace layout (all 16B-aligned)
    char* w = (char*)d_ws;
    u16* Kb   = (u16*)w;  w += (size_t)nPad * HID * 2;  // 25.7 MB
    u16* hhi  = (u16*)w;  w += (size_t)nPad * HID * 2;  // 25.7 MB (reused as agg)
    u16* hlo  = (u16*)w;  w += (size_t)nPad * HID * 2;  // 25.7 MB
    u16* Wqhi = (u16*)w;  w += 512 * 512 * 2;
    u16* Wqlo = (u16*)w;  w += 512 * 512 * 2;
    u16* Wkhi = (u16*)w;  w += 512 * 512 * 2;
    u16* Wklo = (u16*)w;  w += 512 * 512 * 2;
    u16* Wot  = (u16*)w;  w += 512 * 512 * 2;
    float* bqp = (float*)w;  w += 512 * 4;
    float* bkp = (float*)w;  w += 512 * 4;
    int* rowptr = (int*)w;   w += (size_t)(nN + 1) * 4;
    int* cursor = (int*)w;   w += (size_t)nN * 4;
    int* deg    = (int*)w;   w += (size_t)nN * 4;
    int* bsum   = (int*)w;   w += 64 * 4;
    int* eid    = (int*)w;   /* E*4 */

    // CSR build
    hipMemsetAsync(deg, 0, (size_t)nN * sizeof(int), stream);
    hist_kernel<<<(E + 255) / 256, 256, 0, stream>>>(rows, deg, E);
    scan_partial<<<nb, 256, 0, stream>>>(deg, bsum, nN);
    scan_bsum<<<1, 64, 0, stream>>>(bsum, nb, rowptr, nN);
    scan_final<<<nb, 256, 0, stream>>>(deg, bsum, rowptr, cursor, nN);
    scatter_kernel<<<(E + 255) / 256, 256, 0, stream>>>(rows, cursor, eid, E);

    // conversions
    conv_h<<<(nPad * (HID / 8) + 255) / 256, 256, 0, stream>>>(h, hhi, hlo, nN);
    conv_weights<<<1024, 256, 0, stream>>>(Wq, Wk, Wo, bq, bk,
                                           Wqhi, Wqlo, Wkhi, Wklo, Wot, bqp, bkp);

    // projections (head-major outputs); split-bf16 3-pass for accuracy
    dim3 gg(nPad / 128, HID / 128);
    gemm_mfma<1, 0><<<gg, 256, 0, stream>>>(hhi, hlo, Wqhi, Wqlo, bqp, Q,  nN);    // Q f32
    gemm_mfma<1, 1><<<gg, 256, 0, stream>>>(hhi, hlo, Wkhi, Wklo, bkp, Kb, nPad);  // K bf16

    // fused SDDMM + softmax + aggregate -> bf16 agg (overwrites hhi)
    node_agg<<<nPad / 4, 256, 0, stream>>>(Q, Kb, rowptr, eid, cols, hhi, nN, nPad);

    // output projection (single bf16 pass)
    gemm_mfma<0, 0><<<gg, 256, 0, stream>>>(hhi, nullptr, Wot, nullptr, bo, out, nN);
}

// Round 4
// 311.861 us; speedup vs baseline: 3.2198x; 1.1251x over previous
//
#include <hip/hip_runtime.h>
#include <math.h>

typedef unsigned short u16;
typedef unsigned int u32;
typedef __attribute__((ext_vector_type(8))) short short8;    // bf16x8 MFMA frag
typedef __attribute__((ext_vector_type(8))) u16 ushort8;
typedef __attribute__((ext_vector_type(4))) float f32x4;

__device__ __forceinline__ float bf2f(u16 u) {
    union { u32 i; float f; } c; c.i = ((u32)u) << 16; return c.f;
}
__device__ __forceinline__ u16 f2bf(float f) {
    union { float f; u32 i; } c; c.f = f;
    u32 r = (c.i + 0x7FFFu + ((c.i >> 16) & 1u)) >> 16;
    return (u16)r;
}

// async global(16B) -> LDS, per-lane source addr, wave-linear LDS dest
__device__ __forceinline__ void gload16(void* lds, const void* g) {
    __builtin_amdgcn_global_load_lds(
        (const __attribute__((address_space(1))) u32*)g,
        (__attribute__((address_space(3))) u32*)lds,
        16, 0, 0);
}

// ---------------------------------------------------------------------------
// C[M,512] = A[M,512] @ Bt[512,512]([n][k]) + bias.
// SPLIT=1: A,B given as bf16 hi+lo pairs; C = Ahi*Bhi + Alo*Bhi + Ahi*Blo.
// OUTMODE 0: f32 store, 1: bf16 store. Stores guarded by row < Mout.
// ---------------------------------------------------------------------------
template <int SPLIT, int OUTMODE>
__global__ __launch_bounds__(256) void gemm_mfma(
    const u16* __restrict__ Ahi, const u16* __restrict__ Alo,
    const u16* __restrict__ Bhi, const u16* __restrict__ Blo,
    const float* __restrict__ bias, void* __restrict__ Cout, int Mout)
{
    constexpr int NB = SPLIT ? 2 : 1;
    __shared__ u16 As[NB][128 * 32];
    __shared__ u16 Bs[NB][128 * 32];

    const int tid  = threadIdx.x;
    const int wave = tid >> 6;
    const int lane = tid & 63;
    const int m0 = blockIdx.x * 128;
    const int n0 = blockIdx.y * 128;
    const int wr = (wave >> 1) * 64;
    const int wc = (wave & 1) * 64;

    f32x4 acc[4][4];
#pragma unroll
    for (int i = 0; i < 4; ++i)
#pragma unroll
        for (int j = 0; j < 4; ++j) acc[i][j] = (f32x4){0.f, 0.f, 0.f, 0.f};

    // staging: wave handles rows wave*32 .. +31 of the 128-row tile
    const int srow = lane >> 2;          // 0..15 within 16-row chunk
    const int scol = (lane & 3) * 8;     // bf16 elems
    const size_t gOffA = (size_t)(m0 + wave * 32 + srow) * 512 + scol;
    const size_t gOffB = (size_t)(n0 + wave * 32 + srow) * 512 + scol;
    const int lOff = wave * 1024 + srow * 32 + scol;   // == wave_base + lane*16B

    const int paOff = (wr + (lane & 15)) * 32 + (lane >> 4) * 8;
    const int pbOff = (wc + (lane & 15)) * 32 + (lane >> 4) * 8;

    for (int kt = 0; kt < 16; ++kt) {
        const int ko = kt * 32;
        gload16(&As[0][lOff],       Ahi + gOffA + ko);
        gload16(&As[0][lOff + 512], Ahi + gOffA + ko + 16 * 512);
        gload16(&Bs[0][lOff],       Bhi + gOffB + ko);
        gload16(&Bs[0][lOff + 512], Bhi + gOffB + ko + 16 * 512);
        if constexpr (SPLIT) {
            gload16(&As[1][lOff],       Alo + gOffA + ko);
            gload16(&As[1][lOff + 512], Alo + gOffA + ko + 16 * 512);
            gload16(&Bs[1][lOff],       Blo + gOffB + ko);
            gload16(&Bs[1][lOff + 512], Blo + gOffB + ko + 16 * 512);
        }
        __syncthreads();   // compiler drains vmcnt before barrier

        short8 af[NB][4], bf[NB][4];
#pragma unroll
        for (int i = 0; i < 4; ++i) af[0][i] = *(const short8*)(&As[0][paOff + i * 16 * 32]);
#pragma unroll
        for (int j = 0; j < 4; ++j) bf[0][j] = *(const short8*)(&Bs[0][pbOff + j * 16 * 32]);
        if constexpr (SPLIT) {
#pragma unroll
            for (int i = 0; i < 4; ++i) af[1][i] = *(const short8*)(&As[1][paOff + i * 16 * 32]);
#pragma unroll
            for (int j = 0; j < 4; ++j) bf[1][j] = *(const short8*)(&Bs[1][pbOff + j * 16 * 32]);
        }
#pragma unroll
        for (int i = 0; i < 4; ++i)
#pragma unroll
            for (int j = 0; j < 4; ++j) {
                acc[i][j] = __builtin_amdgcn_mfma_f32_16x16x32_bf16(
                    af[0][i], bf[0][j], acc[i][j], 0, 0, 0);
                if constexpr (SPLIT) {
                    acc[i][j] = __builtin_amdgcn_mfma_f32_16x16x32_bf16(
                        af[1][i], bf[0][j], acc[i][j], 0, 0, 0);
                    acc[i][j] = __builtin_amdgcn_mfma_f32_16x16x32_bf16(
                        af[0][i], bf[1][j], acc[i][j], 0, 0, 0);
                }
            }
        __syncthreads();
    }

    // epilogue: C/D layout col=lane&15, row=(lane>>4)*4+reg
    const int ccol  = n0 + wc + (lane & 15);
    const int crow0 = m0 + wr + (lane >> 4) * 4;
#pragma unroll
    for (int j = 0; j < 4; ++j) {
        const float b = bias[ccol + j * 16];
#pragma unroll
        for (int i = 0; i < 4; ++i) {
#pragma unroll
            for (int r = 0; r < 4; ++r) {
                int row = crow0 + i * 16 + r;
                if (row < Mout) {
                    float v = acc[i][j][r] + b;
                    size_t off = (size_t)row * 512 + ccol + j * 16;
                    if (OUTMODE == 0) ((float*)Cout)[off] = v;
                    else              ((u16*)Cout)[off] = f2bf(v);
                }
            }
        }
    }
}

// ---------------------------------------------------------------------------
// prep: h f32 -> bf16 hi+lo, pad rows zeroed
// ---------------------------------------------------------------------------
__global__ __launch_bounds__(256) void conv_h(
    const float* __restrict__ h, u16* __restrict__ hhi, u16* __restrict__ hlo, int nN)
{
    int t = blockIdx.x * 256 + threadIdx.x;      // one thread = 8 elems
    size_t e = (size_t)t * 8;
    int row = (int)(e >> 9);
    ushort8 ohi, olo;
    if (row < nN) {
        f32x4 a = *(const f32x4*)(h + e);
        f32x4 b = *(const f32x4*)(h + e + 4);
        float x[8] = {a.x, a.y, a.z, a.w, b.x, b.y, b.z, b.w};
#pragma unroll
        for (int i = 0; i < 8; ++i) {
            u16 hi = f2bf(x[i]);
            ohi[i] = hi;
            olo[i] = f2bf(x[i] - bf2f(hi));
        }
    } else {
        ohi = (ushort8){0,0,0,0,0,0,0,0};
        olo = (ushort8){0,0,0,0,0,0,0,0};
    }
    *(ushort8*)(hhi + e) = ohi;
    *(ushort8*)(hlo + e) = olo;
}

// weight/bias conversions.
// Wq: Wt[j][k] = W[k][perm(j)] hi+lo  (B^T + head-major col perm)
// Wk: hi only. Wo: Wot[c][j] = bf16(Wo[perm(j)][c])
__global__ __launch_bounds__(256) void conv_weights(
    const float* __restrict__ Wq, const float* __restrict__ Wk,
    const float* __restrict__ Wo, const float* __restrict__ bq,
    const float* __restrict__ bk,
    u16* __restrict__ Wqhi, u16* __restrict__ Wqlo,
    u16* __restrict__ Wkhi,
    u16* __restrict__ Wot, float* __restrict__ bqp, float* __restrict__ bkp)
{
    int t = blockIdx.x * 256 + threadIdx.x;
    if (t >= 512 * 512) return;
    int j = t >> 9, k = t & 511;
    int p = (j & 63) * 8 + (j >> 6);
    float wq = Wq[k * 512 + p];
    u16 hi = f2bf(wq);
    Wqhi[t] = hi; Wqlo[t] = f2bf(wq - bf2f(hi));
    Wkhi[t] = f2bf(Wk[k * 512 + p]);
    // Wo with row-perm, transposed: t = c*512 + j2
    int c = t >> 9, j2 = t & 511;
    int p2 = (j2 & 63) * 8 + (j2 >> 6);
    Wot[t] = f2bf(Wo[p2 * 512 + c]);
    if (t < 512) {
        int pp = (t & 63) * 8 + (t >> 6);
        bqp[t] = bq[pp];
        bkp[t] = bk[pp];
    }
}

// ---------------------------------------------------------------------------
// CSR build: histogram -> hierarchical scan -> scatter (stores cols directly)
// ---------------------------------------------------------------------------
__global__ void hist_kernel(const int* __restrict__ rows, int* __restrict__ deg, int E)
{
    int i = blockIdx.x * 256 + threadIdx.x;
    if (i < E) atomicAdd(&deg[rows[i]], 1);
}

#define SCAN_CHUNK 2048

__global__ __launch_bounds__(256) void scan_partial(
    const int* __restrict__ deg, int* __restrict__ bsum, int n)
{
    int base = blockIdx.x * SCAN_CHUNK;
    int t = threadIdx.x;
    int s = 0;
    for (int i = t; i < SCAN_CHUNK; i += 256) {
        int g = base + i;
        s += (g < n) ? deg[g] : 0;
    }
#pragma unroll
    for (int off = 1; off < 64; off <<= 1) s += __shfl_xor(s, off, 64);
    __shared__ int ws[4];
    if ((t & 63) == 0) ws[t >> 6] = s;
    __syncthreads();
    if (t == 0) bsum[blockIdx.x] = ws[0] + ws[1] + ws[2] + ws[3];
}

__global__ __launch_bounds__(64) void scan_bsum(
    int* __restrict__ bsum, int nb, int* __restrict__ rowptr, int n)
{
    int l = threadIdx.x;
    int v = (l < nb) ? bsum[l] : 0;
    int orig = v;
#pragma unroll
    for (int off = 1; off < 64; off <<= 1) {
        int x = __shfl_up(v, off, 64);
        if (l >= off) v += x;
    }
    if (l < nb) bsum[l] = v - orig;       // exclusive
    if (l == nb - 1) rowptr[n] = v;       // total
}

__global__ __launch_bounds__(256) void scan_final(
    const int* __restrict__ deg, const int* __restrict__ bsum,
    int* __restrict__ rowptr, int* __restrict__ cursor, int n)
{
    int t = threadIdx.x;
    int base = blockIdx.x * SCAN_CHUNK + t * 8;
    int v[8];
    int s = 0;
#pragma unroll
    for (int i = 0; i < 8; ++i) {
        int g = base + i;
        v[i] = (g < n) ? deg[g] : 0;
        s += v[i];
    }
    int lane = t & 63, w = t >> 6;
    int inc = s;
#pragma unroll
    for (int off = 1; off < 64; off <<= 1) {
        int x = __shfl_up(inc, off, 64);
        if (lane >= off) inc += x;
    }
    __shared__ int wsum[4];
    if (lane == 63) wsum[w] = inc;
    __syncthreads();
    int excl = bsum[blockIdx.x] + inc - s;
    for (int i = 0; i < w; ++i) excl += wsum[i];
#pragma unroll
    for (int i = 0; i < 8; ++i) {
        int g = base + i;
        if (g < n) { rowptr[g] = excl; cursor[g] = excl; }
        excl += v[i];
    }
}

__global__ void scatter_kernel(const int* __restrict__ rows, const int* __restrict__ cols,
                               int* __restrict__ cursor, int* __restrict__ colc, int E)
{
    int i = blockIdx.x * 256 + threadIdx.x;
    if (i < E) {
        int pos = atomicAdd(&cursor[rows[i]], 1);
        colc[pos] = cols[i];
    }
}

// ---------------------------------------------------------------------------
// Fused SDDMM + online segment softmax + SpMM. Head-major layout:
// lane l -> head l>>3, dims (l&7)*8..+7. One wave per node, 2 nodes/block.
// Depth-1 prefetch: next edge's K row loads while current edge computes.
// v == k (source bug): K row loaded for the dot is reused for aggregation.
// ---------------------------------------------------------------------------
__global__ __launch_bounds__(128) void node_agg(
    const float* __restrict__ Q, const u16* __restrict__ Kb,
    const int* __restrict__ rowptr, const int* __restrict__ colc,
    u16* __restrict__ aggb, int nN)
{
    int node = blockIdx.x * 2 + (threadIdx.x >> 6);
    int lane = threadIdx.x & 63;
    if (node >= nN) return;
    size_t base = (size_t)node * 512 + lane * 8;

    float q[8];
    {
        f32x4 qa = *(const f32x4*)(Q + base);
        f32x4 qb = *(const f32x4*)(Q + base + 4);
#pragma unroll
        for (int i = 0; i < 4; ++i) { q[i] = qa[i]; q[i + 4] = qb[i]; }
    }

    int start = rowptr[node];
    int end   = rowptr[node + 1];

    float m = -__builtin_inff();
    float den = 0.f;
    float acc[8];
#pragma unroll
    for (int i = 0; i < 8; ++i) acc[i] = 0.f;

    if (end > start) {
        const size_t loff = (size_t)lane * 8;
        ushort8 kv = *(const ushort8*)(Kb + (size_t)colc[start] * 512 + loff);
        for (int j = start; j < end; ++j) {
            float kf[8];
#pragma unroll
            for (int i = 0; i < 8; ++i) kf[i] = bf2f(kv[i]);
            if (j + 1 < end)
                kv = *(const ushort8*)(Kb + (size_t)colc[j + 1] * 512 + loff);

            float p = 0.f;
#pragma unroll
            for (int i = 0; i < 8; ++i) p = fmaf(q[i], kf[i], p);
            p += __shfl_xor(p, 1, 64);
            p += __shfl_xor(p, 2, 64);
            p += __shfl_xor(p, 4, 64);

            // defer-max (T13, THR=8): rescale only when max grows materially
            if (p > m + 8.f) {
                float sc = __expf(m - p);   // first edge: exp(-inf)=0
                den *= sc;
#pragma unroll
                for (int i = 0; i < 8; ++i) acc[i] *= sc;
                m = p;
            }
            float w = __expf(p - m);        // bounded by e^8
            den += w;
#pragma unroll
            for (int i = 0; i < 8; ++i) acc[i] = fmaf(w, kf[i], acc[i]);
        }
    }

    float inv = (end > start) ? 1.f / den : 0.f;
    ushort8 o;
#pragma unroll
    for (int i = 0; i < 8; ++i) o[i] = f2bf(acc[i] * inv);
    *(ushort8*)(aggb + base) = o;
}

// ---------------------------------------------------------------------------
extern "C" void kernel_launch(void* const* d_in, const int* in_sizes, int n_in,
                              void* d_out, int out_size, void* d_ws, size_t ws_size,
                              hipStream_t stream)
{
    const float* h  = (const float*)d_in[0];
    const float* Wq = (const float*)d_in[1];
    const float* bq = (const float*)d_in[2];
    const float* Wk = (const float*)d_in[3];
    const float* bk = (const float*)d_in[4];
    const float* Wo = (const float*)d_in[5];
    const float* bo = (const float*)d_in[6];
    const int* rows = (const int*)d_in[7];
    const int* cols = (const int*)d_in[8];
    float* out = (float*)d_out;

    const int HID = 512;
    const int nN  = in_sizes[0] / HID;              // 25000
    const int E   = in_sizes[7];                    // 400000
    const int nPad = (nN + 127) & ~127;             // 25088
    const int nb = (nN + SCAN_CHUNK - 1) / SCAN_CHUNK;  // 13

    // Q (f32) lives in d_out: it is fully consumed by node_agg before the
    // final Wo GEMM overwrites d_out with the real output.
    float* Q = out;

    // workspace layout (all 16B-aligned)
    char* w = (char*)d_ws;
    u16* Kb   = (u16*)w;  w += (size_t)nPad * HID * 2;  // 25.7 MB
    u16* hhi  = (u16*)w;  w += (size_t)nPad * HID * 2;  // 25.7 MB (reused as agg)
    u16* hlo  = (u16*)w;  w += (size_t)nPad * HID * 2;  // 25.7 MB
    u16* Wqhi = (u16*)w;  w += 512 * 512 * 2;
    u16* Wqlo = (u16*)w;  w += 512 * 512 * 2;
    u16* Wkhi = (u16*)w;  w += 512 * 512 * 2;
    u16* Wot  = (u16*)w;  w += 512 * 512 * 2;
    float* bqp = (float*)w;  w += 512 * 4;
    float* bkp = (float*)w;  w += 512 * 4;
    int* rowptr = (int*)w;   w += (size_t)(nN + 1) * 4;
    int* cursor = (int*)w;   w += (size_t)nN * 4;
    int* deg    = (int*)w;   w += (size_t)nN * 4;
    int* bsum   = (int*)w;   w += 64 * 4;
    int* colc   = (int*)w;   /* E*4 */

    // CSR build
    hipMemsetAsync(deg, 0, (size_t)nN * sizeof(int), stream);
    hist_kernel<<<(E + 255) / 256, 256, 0, stream>>>(rows, deg, E);
    scan_partial<<<nb, 256, 0, stream>>>(deg, bsum, nN);
    scan_bsum<<<1, 64, 0, stream>>>(bsum, nb, rowptr, nN);
    scan_final<<<nb, 256, 0, stream>>>(deg, bsum, rowptr, cursor, nN);
    scatter_kernel<<<(E + 255) / 256, 256, 0, stream>>>(rows, cols, cursor, colc, E);

    // conversions
    conv_h<<<(nPad * (HID / 8) + 255) / 256, 256, 0, stream>>>(h, hhi, hlo, nN);
    conv_weights<<<1024, 256, 0, stream>>>(Wq, Wk, Wo, bq, bk,
                                           Wqhi, Wqlo, Wkhi, Wot, bqp, bkp);

    // projections (head-major outputs); Q split-bf16 3-pass, K single-pass
    dim3 gg(nPad / 128, HID / 128);
    gemm_mfma<1, 0><<<gg, 256, 0, stream>>>(hhi, hlo, Wqhi, Wqlo, bqp, Q,  nN);    // Q f32
    gemm_mfma<0, 1><<<gg, 256, 0, stream>>>(hhi, nullptr, Wkhi, nullptr, bkp, Kb, nPad); // K bf16

    // fused SDDMM + softmax + aggregate -> bf16 agg (overwrites hhi)
    node_agg<<<(nN + 1) / 2, 128, 0, stream>>>(Q, Kb, rowptr, colc, hhi, nN);

    // output projection (single bf16 pass)
    gemm_mfma<0, 0><<<gg, 256, 0, stream>>>(hhi, nullptr, Wot, nullptr, bo, out, nN);
}